// Round 1
// baseline (1246.145 us; speedup 1.0000x reference)
//
#include <hip/hip_runtime.h>
#include <cstdint>
#include <cstddef>

// Problem constants (match reference config)
#define TT   4096     // tokens
#define HH   1024     // hidden
#define II   512      // moe intermediate
#define EE   64       // experts
#define KT   8        // top-k
#define ISZ  1024     // shared intermediate (I*NSH)
#define TKA  32768    // T*K assignments
#define MAXT 320      // max M-tiles: sum ceil(n_e/128) <= 256+64

typedef __bf16 bf16x8 __attribute__((ext_vector_type(8)));
typedef float  f32x4  __attribute__((ext_vector_type(4)));

__device__ __forceinline__ unsigned short f2bf(float f) {
  unsigned u = __float_as_uint(f);
  u += 0x7fffu + ((u >> 16) & 1u);   // RNE (finite inputs only)
  return (unsigned short)(u >> 16);
}

// async global->LDS, 16B/lane; LDS dest is wave-uniform base + lane*16
#define GLDS(gp, lp) __builtin_amdgcn_global_load_lds( \
    (const __attribute__((address_space(1))) void*)(gp), \
    (__attribute__((address_space(3))) void*)(lp), 16, 0, 0)

// ---------------- transpose + fp32->bf16 convert: in[b][R][C] -> out[b][C][R]
__global__ __launch_bounds__(256) void k_transpose(const float* __restrict__ in,
                                                   unsigned short* __restrict__ out,
                                                   int R, int C) {
  __shared__ float tile[64][65];
  long b = blockIdx.z;
  int r0 = blockIdx.x * 64, c0 = blockIdx.y * 64;
  const float* ip = in + b * (long)R * C;
  unsigned short* op = out + b * (long)R * C;
  int tc = threadIdx.x & 63, tr = threadIdx.x >> 6;
#pragma unroll
  for (int rr = 0; rr < 64; rr += 4)
    tile[tr + rr][tc] = ip[(long)(r0 + tr + rr) * C + (c0 + tc)];
  __syncthreads();
#pragma unroll
  for (int rr = 0; rr < 64; rr += 4)
    op[(long)(c0 + tr + rr) * R + (r0 + tc)] = f2bf(tile[tc][tr + rr]);
}

// ---------------- fp32 -> bf16 elementwise (x)
__global__ __launch_bounds__(256) void k_cvt(const float* __restrict__ in,
                                             unsigned short* __restrict__ out) {
  int i = blockIdx.x * 256 + threadIdx.x;
  float4 v = ((const float4*)in)[i];
  ushort4 o;
  o.x = f2bf(v.x); o.y = f2bf(v.y); o.z = f2bf(v.z); o.w = f2bf(v.w);
  ((ushort4*)out)[i] = o;
}

// ---------------- router: fp64-accurate logits -> sigmoid -> grouped top-k
__global__ __launch_bounds__(256) void k_router(const float* __restrict__ x,
    const float* __restrict__ gw, const float* __restrict__ eb,
    int* __restrict__ topk_ids, float* __restrict__ topk_w, int* __restrict__ counts)
{
  __shared__ float xrow[HH];
  __shared__ float sc[EE];
  int t = blockIdx.x;
  int tid = threadIdx.x;
  for (int i = tid; i < HH; i += 256) xrow[i] = x[(long)t * HH + i];
  __syncthreads();
  int e = tid >> 2, q = tid & 3;          // 4 threads per expert
  const float* w = gw + (long)e * HH;
  double acc = 0.0;
  for (int i = q * 4; i < HH; i += 16) {
    float4 wv = *(const float4*)(w + i);
    acc += (double)wv.x * (double)xrow[i]
         + (double)wv.y * (double)xrow[i + 1]
         + (double)wv.z * (double)xrow[i + 2]
         + (double)wv.w * (double)xrow[i + 3];
  }
  acc += __shfl_down(acc, 2);
  acc += __shfl_down(acc, 1);
  if (q == 0) sc[e] = (float)(1.0 / (1.0 + exp(-acc)));
  __syncthreads();
  if (tid == 0) {
    float s[EE], sfc[EE];
    for (int i = 0; i < EE; i++) { s[i] = sc[i]; sfc[i] = sc[i] + eb[i]; }
    float gs[8];
    for (int g = 0; g < 8; g++) {            // group score = sum of top-2
      float m1 = -1e30f, m2 = -1e30f;
      for (int j = 0; j < 8; j++) {
        float v = sfc[g * 8 + j];
        if (v > m1) { m2 = m1; m1 = v; } else if (v > m2) m2 = v;
      }
      gs[g] = m1 + m2;
    }
    bool gsel[8] = {false,false,false,false,false,false,false,false};
    for (int it = 0; it < 4; it++) {         // top-4 groups, ties -> lowest idx
      float best = -1e30f; int bi = 0;
      for (int g = 0; g < 8; g++) if (!gsel[g] && gs[g] > best) { best = gs[g]; bi = g; }
      gsel[bi] = true;
    }
    bool esel[EE];
    for (int i = 0; i < EE; i++) esel[i] = false;
    int ids[KT]; float wv[KT]; float wsum = 0.f;
    for (int it = 0; it < KT; it++) {        // top-8 of masked sfc (masked -> 0.0)
      float best = -1e30f; int bi = 0;
      for (int i = 0; i < EE; i++) {
        if (esel[i]) continue;
        float v = gsel[i >> 3] ? sfc[i] : 0.0f;
        if (v > best) { best = v; bi = i; }
      }
      esel[bi] = true; ids[it] = bi; wv[it] = s[bi]; wsum += s[bi];
    }
    for (int k = 0; k < KT; k++) {
      topk_ids[(long)t * KT + k] = ids[k];
      topk_w[(long)t * KT + k] = wv[k] / wsum;
      atomicAdd(&counts[ids[k]], 1);
    }
  }
}

// ---------------- offsets + static tile table (single block)
__global__ void k_offsets(const int* __restrict__ counts, int* __restrict__ offsets,
                          int* __restrict__ cursor, int* __restrict__ tile_e,
                          int* __restrict__ tile_r0)
{
  if (threadIdx.x != 0) return;
  int off = 0;
  for (int e = 0; e < EE; e++) { offsets[e] = off; cursor[e] = off; off += counts[e]; }
  offsets[EE] = off;
  int nt = 0;
  for (int e = 0; e < EE; e++)
    for (int r = offsets[e]; r < offsets[e + 1]; r += 128) { tile_e[nt] = e; tile_r0[nt] = r; nt++; }
  for (; nt < MAXT; nt++) tile_e[nt] = -1;
}

// ---------------- scatter assignments into expert-sorted slot order
__global__ __launch_bounds__(256) void k_scatter(const int* __restrict__ ids,
    const float* __restrict__ tw, int* __restrict__ cursor,
    int* __restrict__ perm, float* __restrict__ wslot)
{
  int a = blockIdx.x * 256 + threadIdx.x;
  int e = ids[a];
  int pos = atomicAdd(&cursor[e], 1);
  perm[pos] = a >> 3;     // token index
  wslot[pos] = tw[a];
}

// ---------------- GEMM1 (gate_up) + fused silu*mul. Twin accumulators:
// block: 128 rows x 64 gate cols + 64 up cols. 4 waves (2x2), 16x16x32 bf16 MFMA.
__global__ __launch_bounds__(256) void k_gemm_gu(
    const unsigned short* __restrict__ Abase, const int* __restrict__ perm,
    const unsigned short* __restrict__ Bbase, long eStride, int Kd, int upOff,
    unsigned short* __restrict__ Hout,
    const int* __restrict__ tile_e, const int* __restrict__ tile_r0,
    const int* __restrict__ eoff, int rowsTotal)
{
  __shared__ __align__(16) unsigned short lds[8192];  // A 4096 | Bg 2048 | Bu 2048
  int e = 0, row0, end;
  if (tile_e) {
    e = tile_e[blockIdx.x];
    if (e < 0) return;
    row0 = tile_r0[blockIdx.x];
    end = eoff[e + 1];
  } else { row0 = blockIdx.x * 128; end = rowsTotal; }
  const unsigned short* B = Bbase + (long)e * eStride;
  int n0 = blockIdx.y * 64;
  int tid = threadIdx.x, lane = tid & 63, wave = tid >> 6;
  int wm = wave >> 1, wn = wave & 1;
  int lr = lane >> 2, lk = (lane & 3) * 8;
  int r0a = row0 + wave * 32 + lr;
  int r1a = r0a + 16;
  int t0 = r0a < rowsTotal ? r0a : rowsTotal - 1;
  int t1 = r1a < rowsTotal ? r1a : rowsTotal - 1;
  if (perm) { t0 = perm[t0]; t1 = perm[t1]; }
  const unsigned short* ap0 = Abase + (long)t0 * Kd + lk;
  const unsigned short* ap1 = Abase + (long)t1 * Kd + lk;
  const unsigned short* bg = B + (long)(n0 + wave * 16 + lr) * Kd + lk;
  const unsigned short* bu = B + (long)(upOff + n0 + wave * 16 + lr) * Kd + lk;
  unsigned short* lA0 = lds + wave * 1024 + lane * 8;          // rows wave*32..  (+512 = +16 rows)
  unsigned short* lBg = lds + 4096 + wave * 512 + lane * 8;    // rows wave*16..
  unsigned short* lBu = lds + 6144 + wave * 512 + lane * 8;
  f32x4 acc[4][4];
  f32x4 z = {0.f, 0.f, 0.f, 0.f};
  for (int i = 0; i < 4; i++) for (int j = 0; j < 4; j++) acc[i][j] = z;
  int quad = lane >> 4, cl = lane & 15;
  for (int k0 = 0; k0 < Kd; k0 += 32) {
    __syncthreads();
    GLDS(ap0 + k0, lA0);
    GLDS(ap1 + k0, lA0 + 512);
    GLDS(bg + k0, lBg);
    GLDS(bu + k0, lBu);
    __syncthreads();
    bf16x8 af[4], bgf[2], buf2[2];
#pragma unroll
    for (int mi = 0; mi < 4; mi++)
      af[mi] = *(const bf16x8*)(lds + (wm * 64 + mi * 16 + cl) * 32 + quad * 8);
#pragma unroll
    for (int ni = 0; ni < 2; ni++) {
      bgf[ni]  = *(const bf16x8*)(lds + 4096 + (wn * 32 + ni * 16 + cl) * 32 + quad * 8);
      buf2[ni] = *(const bf16x8*)(lds + 6144 + (wn * 32 + ni * 16 + cl) * 32 + quad * 8);
    }
#pragma unroll
    for (int mi = 0; mi < 4; mi++) {
#pragma unroll
      for (int ni = 0; ni < 2; ni++) {
        acc[mi][ni]     = __builtin_amdgcn_mfma_f32_16x16x32_bf16(af[mi], bgf[ni],  acc[mi][ni],     0, 0, 0);
        acc[mi][ni + 2] = __builtin_amdgcn_mfma_f32_16x16x32_bf16(af[mi], buf2[ni], acc[mi][ni + 2], 0, 0, 0);
      }
    }
  }
#pragma unroll
  for (int mi = 0; mi < 4; mi++) {
#pragma unroll
    for (int j = 0; j < 2; j++) {
#pragma unroll
      for (int r = 0; r < 4; r++) {
        int row = row0 + wm * 64 + mi * 16 + quad * 4 + r;
        if (row < end) {
          float g = acc[mi][j][r], u = acc[mi][j + 2][r];
          float hv = g * (1.f / (1.f + __expf(-g))) * u;   // silu(g)*u
          Hout[(long)row * upOff + (n0 + wn * 32 + j * 16 + cl)] = f2bf(hv);
        }
      }
    }
  }
}

// ---------------- GEMM2 (down). 128x128 tile; epilogue: plain store (shared)
// or scaled unsafeAtomicAdd into out (routed combine).
__global__ __launch_bounds__(256) void k_gemm_down(
    const unsigned short* __restrict__ Abase,
    const unsigned short* __restrict__ Bbase, long eStride, int Kd,
    float* __restrict__ Out,
    const int* __restrict__ perm, const float* __restrict__ wslot,
    const int* __restrict__ tile_e, const int* __restrict__ tile_r0,
    const int* __restrict__ eoff, int rowsTotal, int doAtomic)
{
  __shared__ __align__(16) unsigned short lds[8192];  // A 4096 | B 4096
  int e = 0, row0, end;
  if (tile_e) {
    e = tile_e[blockIdx.x];
    if (e < 0) return;
    row0 = tile_r0[blockIdx.x];
    end = eoff[e + 1];
  } else { row0 = blockIdx.x * 128; end = rowsTotal; }
  const unsigned short* B = Bbase + (long)e * eStride;
  int n0 = blockIdx.y * 128;
  int tid = threadIdx.x, lane = tid & 63, wave = tid >> 6;
  int wm = wave >> 1, wn = wave & 1;
  int lr = lane >> 2, lk = (lane & 3) * 8;
  int r0a = row0 + wave * 32 + lr;
  int r1a = r0a + 16;
  int t0 = r0a < rowsTotal ? r0a : rowsTotal - 1;
  int t1 = r1a < rowsTotal ? r1a : rowsTotal - 1;
  const unsigned short* ap0 = Abase + (long)t0 * Kd + lk;
  const unsigned short* ap1 = Abase + (long)t1 * Kd + lk;
  const unsigned short* bp0 = B + (long)(n0 + wave * 32 + lr) * Kd + lk;
  const unsigned short* bp1 = bp0 + (long)16 * Kd;
  unsigned short* lA0 = lds + wave * 1024 + lane * 8;
  unsigned short* lB0 = lds + 4096 + wave * 1024 + lane * 8;
  f32x4 acc[4][4];
  f32x4 z = {0.f, 0.f, 0.f, 0.f};
  for (int i = 0; i < 4; i++) for (int j = 0; j < 4; j++) acc[i][j] = z;
  int quad = lane >> 4, cl = lane & 15;
  for (int k0 = 0; k0 < Kd; k0 += 32) {
    __syncthreads();
    GLDS(ap0 + k0, lA0);
    GLDS(ap1 + k0, lA0 + 512);
    GLDS(bp0 + k0, lB0);
    GLDS(bp1 + k0, lB0 + 512);
    __syncthreads();
    bf16x8 af[4], bfr[4];
#pragma unroll
    for (int mi = 0; mi < 4; mi++)
      af[mi] = *(const bf16x8*)(lds + (wm * 64 + mi * 16 + cl) * 32 + quad * 8);
#pragma unroll
    for (int ni = 0; ni < 4; ni++)
      bfr[ni] = *(const bf16x8*)(lds + 4096 + (wn * 64 + ni * 16 + cl) * 32 + quad * 8);
#pragma unroll
    for (int mi = 0; mi < 4; mi++)
#pragma unroll
      for (int ni = 0; ni < 4; ni++)
        acc[mi][ni] = __builtin_amdgcn_mfma_f32_16x16x32_bf16(af[mi], bfr[ni], acc[mi][ni], 0, 0, 0);
  }
#pragma unroll
  for (int mi = 0; mi < 4; mi++) {
    int rowb = row0 + wm * 64 + mi * 16 + quad * 4;
#pragma unroll
    for (int r = 0; r < 4; r++) {
      int row = rowb + r;
      if (row >= end) continue;
      long orow = row;
      float scale = 1.f;
      if (doAtomic) { orow = perm[row]; scale = wslot[row] * 2.5f; }
#pragma unroll
      for (int ni = 0; ni < 4; ni++) {
        int col = n0 + wn * 64 + ni * 16 + cl;
        float v = acc[mi][ni][r] * scale;
        if (doAtomic) unsafeAtomicAdd(&Out[orow * HH + col], v);
        else          Out[orow * HH + col] = v;
      }
    }
  }
}

extern "C" void kernel_launch(void* const* d_in, const int* in_sizes, int n_in,
                              void* d_out, int out_size, void* d_ws, size_t ws_size,
                              hipStream_t stream)
{
  const float* x   = (const float*)d_in[0];
  const float* gw  = (const float*)d_in[1];
  const float* eb  = (const float*)d_in[2];
  const float* w1  = (const float*)d_in[3];
  const float* w2  = (const float*)d_in[4];
  const float* sgu = (const float*)d_in[5];
  const float* sd  = (const float*)d_in[6];
  float* out = (float*)d_out;
  char* ws = (char*)d_ws;
  size_t off = 0;
  auto alloc = [&](size_t b) { void* p = ws + off; off += (b + 255) & ~(size_t)255; return p; };
  unsigned short* w1t  = (unsigned short*)alloc((size_t)EE * 2 * II * HH * 2);  // [E][2I][H] bf16
  unsigned short* w2t  = (unsigned short*)alloc((size_t)EE * HH * II * 2);      // [E][H][I]
  unsigned short* sgut = (unsigned short*)alloc((size_t)2 * ISZ * HH * 2);      // [2IS][H]
  unsigned short* sdt  = (unsigned short*)alloc((size_t)HH * ISZ * 2);          // [H][IS]
  unsigned short* xb   = (unsigned short*)alloc((size_t)TT * HH * 2);           // x bf16
  unsigned short* hsb  = (unsigned short*)alloc((size_t)TT * ISZ * 2);          // shared h
  unsigned short* hb   = (unsigned short*)alloc((size_t)TKA * II * 2);          // routed h
  int*   tids   = (int*)alloc((size_t)TKA * 4);
  float* tw     = (float*)alloc((size_t)TKA * 4);
  int*   counts = (int*)alloc(256);
  int*   offs   = (int*)alloc(512);
  int*   cursor = (int*)alloc(256);
  int*   tile_e = (int*)alloc(MAXT * 4);
  int*   tile_r = (int*)alloc(MAXT * 4);
  int*   perm   = (int*)alloc((size_t)TKA * 4);
  float* wslot  = (float*)alloc((size_t)TKA * 4);

  hipMemsetAsync(counts, 0, 256, stream);
  dim3 b256(256);
  // weight transpose+convert (bf16 [N][K] so MFMA frag reads are K-contiguous)
  k_transpose<<<dim3(HH / 64, (2 * II) / 64, EE), b256, 0, stream>>>(w1, w1t, HH, 2 * II);
  k_transpose<<<dim3(II / 64, HH / 64, EE), b256, 0, stream>>>(w2, w2t, II, HH);
  k_transpose<<<dim3(HH / 64, (2 * ISZ) / 64, 1), b256, 0, stream>>>(sgu, sgut, HH, 2 * ISZ);
  k_transpose<<<dim3(ISZ / 64, HH / 64, 1), b256, 0, stream>>>(sd, sdt, ISZ, HH);
  k_cvt<<<dim3((TT * HH) / 1024), b256, 0, stream>>>(x, xb);
  // routing
  k_router<<<dim3(TT), b256, 0, stream>>>(x, gw, eb, tids, tw, counts);
  k_offsets<<<dim3(1), dim3(64), 0, stream>>>(counts, offs, cursor, tile_e, tile_r);
  k_scatter<<<dim3(TKA / 256), b256, 0, stream>>>(tids, tw, cursor, perm, wslot);
  // routed GEMM1 (gathered A via perm) and shared GEMM1
  k_gemm_gu<<<dim3(MAXT, II / 64), b256, 0, stream>>>(xb, perm, w1t, (long)2 * II * HH, HH, II,
                                                      hb, tile_e, tile_r, offs, TKA);
  k_gemm_gu<<<dim3(TT / 128, ISZ / 64), b256, 0, stream>>>(xb, nullptr, sgut, 0, HH, ISZ,
                                                           hsb, nullptr, nullptr, nullptr, TT);
  // shared GEMM2 writes out; routed GEMM2 atomically adds scaled contributions
  k_gemm_down<<<dim3(TT / 128, HH / 128), b256, 0, stream>>>(hsb, sdt, 0, ISZ, out,
                                                             nullptr, nullptr, nullptr, nullptr,
                                                             nullptr, TT, 0);
  k_gemm_down<<<dim3(MAXT, HH / 128), b256, 0, stream>>>(hb, w2t, (long)HH * II, II, out,
                                                         perm, wslot, tile_e, tile_r, offs, TKA, 1);
}

// Round 2
// 1003.198 us; speedup vs baseline: 1.2422x; 1.2422x over previous
//
#include <hip/hip_runtime.h>
#include <cstdint>
#include <cstddef>

// Problem constants (match reference config)
#define TT   4096     // tokens
#define HH   1024     // hidden
#define II   512      // moe intermediate
#define EE   64       // experts
#define KT   8        // top-k
#define ISZ  1024     // shared intermediate (I*NSH)
#define TKA  32768    // T*K assignments
#define MAXT 320      // max M-tiles: sum ceil(n_e/128) <= 256+64

typedef __bf16 bf16x8 __attribute__((ext_vector_type(8)));
typedef float  f32x4  __attribute__((ext_vector_type(4)));

__device__ __forceinline__ unsigned short f2bf(float f) {
  unsigned u = __float_as_uint(f);
  u += 0x7fffu + ((u >> 16) & 1u);   // RNE (finite inputs only)
  return (unsigned short)(u >> 16);
}

// async global->LDS, 16B/lane; LDS dest is wave-uniform base + lane*16
#define GLDS(gp, lp) __builtin_amdgcn_global_load_lds( \
    (const __attribute__((address_space(1))) void*)(gp), \
    (__attribute__((address_space(3))) void*)(lp), 16, 0, 0)

// ---------------- transpose + fp32->bf16 convert: in[b][R][C] -> out[b][C][R]
__global__ __launch_bounds__(256) void k_transpose(const float* __restrict__ in,
                                                   unsigned short* __restrict__ out,
                                                   int R, int C) {
  __shared__ float tile[64][65];
  long b = blockIdx.z;
  int r0 = blockIdx.x * 64, c0 = blockIdx.y * 64;
  const float* ip = in + b * (long)R * C;
  unsigned short* op = out + b * (long)R * C;
  int tc = threadIdx.x & 63, tr = threadIdx.x >> 6;
#pragma unroll
  for (int rr = 0; rr < 64; rr += 4)
    tile[tr + rr][tc] = ip[(long)(r0 + tr + rr) * C + (c0 + tc)];
  __syncthreads();
#pragma unroll
  for (int rr = 0; rr < 64; rr += 4)
    op[(long)(c0 + tr + rr) * R + (r0 + tc)] = f2bf(tile[tc][tr + rr]);
}

// ---------------- fp32 -> bf16 elementwise (x)
__global__ __launch_bounds__(256) void k_cvt(const float* __restrict__ in,
                                             unsigned short* __restrict__ out) {
  int i = blockIdx.x * 256 + threadIdx.x;
  float4 v = ((const float4*)in)[i];
  ushort4 o;
  o.x = f2bf(v.x); o.y = f2bf(v.y); o.z = f2bf(v.z); o.w = f2bf(v.w);
  ((ushort4*)out)[i] = o;
}

// ---------------- router: fp64-accurate logits -> sigmoid -> wave-parallel
// grouped top-k (lane = expert, all state in registers, shuffles only).
__global__ __launch_bounds__(256) void k_router(const float* __restrict__ x,
    const float* __restrict__ gw, const float* __restrict__ eb,
    int* __restrict__ topk_ids, float* __restrict__ topk_w, int* __restrict__ counts)
{
  __shared__ float xrow[HH];
  __shared__ float sc[EE];
  int t = blockIdx.x;
  int tid = threadIdx.x;
  for (int i = tid; i < HH; i += 256) xrow[i] = x[(long)t * HH + i];
  __syncthreads();
  int e = tid >> 2, q = tid & 3;          // 4 threads per expert
  const float* w = gw + (long)e * HH;
  double acc = 0.0, acc2 = 0.0;           // 2 chains to halve dep latency
  for (int i = q * 8; i < HH; i += 32) {
    float4 wa = *(const float4*)(w + i);
    float4 wb = *(const float4*)(w + i + 4);
    acc  += (double)wa.x * (double)xrow[i]
          + (double)wa.y * (double)xrow[i + 1]
          + (double)wa.z * (double)xrow[i + 2]
          + (double)wa.w * (double)xrow[i + 3];
    acc2 += (double)wb.x * (double)xrow[i + 4]
          + (double)wb.y * (double)xrow[i + 5]
          + (double)wb.z * (double)xrow[i + 6]
          + (double)wb.w * (double)xrow[i + 7];
  }
  acc += acc2;
  acc += __shfl_down(acc, 2);
  acc += __shfl_down(acc, 1);
  if (q == 0) sc[e] = (float)(1.0 / (1.0 + exp(-acc)));
  __syncthreads();
  if (tid < 64) {                          // wave 0, lane = expert
    int lane = tid;
    float s = sc[lane];
    float sfc = s + eb[lane];
    // --- top-2 within each group of 8 lanes (butterfly top-2 merge)
    float m1 = sfc, m2 = -1e30f;
#pragma unroll
    for (int d = 1; d < 8; d <<= 1) {
      float o1 = __shfl_xor(m1, d);
      float o2 = __shfl_xor(m2, d);
      float hi = fmaxf(m1, o1);
      float lo = fminf(m1, o1);
      m2 = fmaxf(lo, fmaxf(m2, o2));
      m1 = hi;
    }
    float gs = m1 + m2;                    // group score (uniform within group)
    int g = lane >> 3;
    // --- rank my group among 8 (ties -> lowest group idx), select top-4
    int grank = 0;
#pragma unroll
    for (int j = 0; j < 8; j++) {
      float gj = __shfl(gs, j * 8);
      if (gj > gs || (gj == gs && j < g)) grank++;
    }
    bool gsel = grank < 4;
    float mv = gsel ? sfc : 0.0f;          // masked_fill(~mask, 0.0) as in ref
    // --- rank among all 64 (ties -> lowest lane), select top-8
    int rank = 0;
    for (int j = 0; j < 64; j++) {
      float vj = __shfl(mv, j);
      if (vj > mv || (vj == mv && j < lane)) rank++;
    }
    bool sel = rank < KT;
    float ssum = sel ? s : 0.0f;           // renorm sum of RAW scores
#pragma unroll
    for (int d = 1; d < 64; d <<= 1) ssum += __shfl_xor(ssum, d);
    unsigned long long bal = __ballot(sel);
    if (sel) {
      int pos = __popcll(bal & ((1ull << lane) - 1ull));
      topk_ids[(long)t * KT + pos] = lane;
      topk_w[(long)t * KT + pos] = s / ssum;
      atomicAdd(&counts[lane], 1);
    }
  }
}

// ---------------- offsets + static tile table (one wave, shuffle prefix sums)
__global__ void k_offsets(const int* __restrict__ counts, int* __restrict__ offsets,
                          int* __restrict__ cursor, int* __restrict__ tile_e,
                          int* __restrict__ tile_r0)
{
  int lane = threadIdx.x;                  // 64 threads = 1 wave
  int c = counts[lane];
  int xs = c;                              // inclusive prefix sum of counts
#pragma unroll
  for (int d = 1; d < 64; d <<= 1) { int y = __shfl_up(xs, d); if (lane >= d) xs += y; }
  int off = xs - c;                        // exclusive
  offsets[lane] = off;
  cursor[lane] = off;
  if (lane == 63) offsets[EE] = xs;
  int nt = (c + 127) >> 7;                 // M-tiles for this expert
  int tp = nt;                             // inclusive prefix sum of tiles
#pragma unroll
  for (int d = 1; d < 64; d <<= 1) { int y = __shfl_up(tp, d); if (lane >= d) tp += y; }
  int tbase = tp - nt;
  for (int i = 0; i < nt; i++) { tile_e[tbase + i] = lane; tile_r0[tbase + i] = off + i * 128; }
  int total = __shfl(tp, 63);
  for (int i = total + lane; i < MAXT; i += 64) tile_e[i] = -1;
}

// ---------------- scatter assignments into expert-sorted slot order
__global__ __launch_bounds__(256) void k_scatter(const int* __restrict__ ids,
    const float* __restrict__ tw, int* __restrict__ cursor,
    int* __restrict__ perm, float* __restrict__ wslot)
{
  int a = blockIdx.x * 256 + threadIdx.x;
  int e = ids[a];
  int pos = atomicAdd(&cursor[e], 1);
  perm[pos] = a >> 3;     // token index
  wslot[pos] = tw[a];
}

// ---------------- GEMM1 (gate_up) + fused silu*mul. Twin accumulators:
// block: 128 rows x 64 gate cols + 64 up cols. 4 waves (2x2), 16x16x32 bf16 MFMA.
__global__ __launch_bounds__(256) void k_gemm_gu(
    const unsigned short* __restrict__ Abase, const int* __restrict__ perm,
    const unsigned short* __restrict__ Bbase, long eStride, int Kd, int upOff,
    unsigned short* __restrict__ Hout,
    const int* __restrict__ tile_e, const int* __restrict__ tile_r0,
    const int* __restrict__ eoff, int rowsTotal)
{
  __shared__ __align__(16) unsigned short lds[8192];  // A 4096 | Bg 2048 | Bu 2048
  int e = 0, row0, end;
  if (tile_e) {
    e = tile_e[blockIdx.x];
    if (e < 0) return;
    row0 = tile_r0[blockIdx.x];
    end = eoff[e + 1];
  } else { row0 = blockIdx.x * 128; end = rowsTotal; }
  const unsigned short* B = Bbase + (long)e * eStride;
  int n0 = blockIdx.y * 64;
  int tid = threadIdx.x, lane = tid & 63, wave = tid >> 6;
  int wm = wave >> 1, wn = wave & 1;
  int lr = lane >> 2, lk = (lane & 3) * 8;
  int r0a = row0 + wave * 32 + lr;
  int r1a = r0a + 16;
  int t0 = r0a < rowsTotal ? r0a : rowsTotal - 1;
  int t1 = r1a < rowsTotal ? r1a : rowsTotal - 1;
  if (perm) { t0 = perm[t0]; t1 = perm[t1]; }
  const unsigned short* ap0 = Abase + (long)t0 * Kd + lk;
  const unsigned short* ap1 = Abase + (long)t1 * Kd + lk;
  const unsigned short* bg = B + (long)(n0 + wave * 16 + lr) * Kd + lk;
  const unsigned short* bu = B + (long)(upOff + n0 + wave * 16 + lr) * Kd + lk;
  unsigned short* lA0 = lds + wave * 1024 + lane * 8;          // rows wave*32..  (+512 = +16 rows)
  unsigned short* lBg = lds + 4096 + wave * 512 + lane * 8;    // rows wave*16..
  unsigned short* lBu = lds + 6144 + wave * 512 + lane * 8;
  f32x4 acc[4][4];
  f32x4 z = {0.f, 0.f, 0.f, 0.f};
  for (int i = 0; i < 4; i++) for (int j = 0; j < 4; j++) acc[i][j] = z;
  int quad = lane >> 4, cl = lane & 15;
  for (int k0 = 0; k0 < Kd; k0 += 32) {
    __syncthreads();
    GLDS(ap0 + k0, lA0);
    GLDS(ap1 + k0, lA0 + 512);
    GLDS(bg + k0, lBg);
    GLDS(bu + k0, lBu);
    __syncthreads();
    bf16x8 af[4], bgf[2], buf2[2];
#pragma unroll
    for (int mi = 0; mi < 4; mi++)
      af[mi] = *(const bf16x8*)(lds + (wm * 64 + mi * 16 + cl) * 32 + quad * 8);
#pragma unroll
    for (int ni = 0; ni < 2; ni++) {
      bgf[ni]  = *(const bf16x8*)(lds + 4096 + (wn * 32 + ni * 16 + cl) * 32 + quad * 8);
      buf2[ni] = *(const bf16x8*)(lds + 6144 + (wn * 32 + ni * 16 + cl) * 32 + quad * 8);
    }
#pragma unroll
    for (int mi = 0; mi < 4; mi++) {
#pragma unroll
      for (int ni = 0; ni < 2; ni++) {
        acc[mi][ni]     = __builtin_amdgcn_mfma_f32_16x16x32_bf16(af[mi], bgf[ni],  acc[mi][ni],     0, 0, 0);
        acc[mi][ni + 2] = __builtin_amdgcn_mfma_f32_16x16x32_bf16(af[mi], buf2[ni], acc[mi][ni + 2], 0, 0, 0);
      }
    }
  }
#pragma unroll
  for (int mi = 0; mi < 4; mi++) {
#pragma unroll
    for (int j = 0; j < 2; j++) {
#pragma unroll
      for (int r = 0; r < 4; r++) {
        int row = row0 + wm * 64 + mi * 16 + quad * 4 + r;
        if (row < end) {
          float g = acc[mi][j][r], u = acc[mi][j + 2][r];
          float hv = g * (1.f / (1.f + __expf(-g))) * u;   // silu(g)*u
          Hout[(long)row * upOff + (n0 + wn * 32 + j * 16 + cl)] = f2bf(hv);
        }
      }
    }
  }
}

// ---------------- GEMM2 (down). 128x128 tile; epilogue: plain store (shared)
// or scaled unsafeAtomicAdd into out (routed combine).
__global__ __launch_bounds__(256) void k_gemm_down(
    const unsigned short* __restrict__ Abase,
    const unsigned short* __restrict__ Bbase, long eStride, int Kd,
    float* __restrict__ Out,
    const int* __restrict__ perm, const float* __restrict__ wslot,
    const int* __restrict__ tile_e, const int* __restrict__ tile_r0,
    const int* __restrict__ eoff, int rowsTotal, int doAtomic)
{
  __shared__ __align__(16) unsigned short lds[8192];  // A 4096 | B 4096
  int e = 0, row0, end;
  if (tile_e) {
    e = tile_e[blockIdx.x];
    if (e < 0) return;
    row0 = tile_r0[blockIdx.x];
    end = eoff[e + 1];
  } else { row0 = blockIdx.x * 128; end = rowsTotal; }
  const unsigned short* B = Bbase + (long)e * eStride;
  int n0 = blockIdx.y * 128;
  int tid = threadIdx.x, lane = tid & 63, wave = tid >> 6;
  int wm = wave >> 1, wn = wave & 1;
  int lr = lane >> 2, lk = (lane & 3) * 8;
  int r0a = row0 + wave * 32 + lr;
  int r1a = r0a + 16;
  int t0 = r0a < rowsTotal ? r0a : rowsTotal - 1;
  int t1 = r1a < rowsTotal ? r1a : rowsTotal - 1;
  const unsigned short* ap0 = Abase + (long)t0 * Kd + lk;
  const unsigned short* ap1 = Abase + (long)t1 * Kd + lk;
  const unsigned short* bp0 = B + (long)(n0 + wave * 32 + lr) * Kd + lk;
  const unsigned short* bp1 = bp0 + (long)16 * Kd;
  unsigned short* lA0 = lds + wave * 1024 + lane * 8;
  unsigned short* lB0 = lds + 4096 + wave * 1024 + lane * 8;
  f32x4 acc[4][4];
  f32x4 z = {0.f, 0.f, 0.f, 0.f};
  for (int i = 0; i < 4; i++) for (int j = 0; j < 4; j++) acc[i][j] = z;
  int quad = lane >> 4, cl = lane & 15;
  for (int k0 = 0; k0 < Kd; k0 += 32) {
    __syncthreads();
    GLDS(ap0 + k0, lA0);
    GLDS(ap1 + k0, lA0 + 512);
    GLDS(bp0 + k0, lB0);
    GLDS(bp1 + k0, lB0 + 512);
    __syncthreads();
    bf16x8 af[4], bfr[4];
#pragma unroll
    for (int mi = 0; mi < 4; mi++)
      af[mi] = *(const bf16x8*)(lds + (wm * 64 + mi * 16 + cl) * 32 + quad * 8);
#pragma unroll
    for (int ni = 0; ni < 4; ni++)
      bfr[ni] = *(const bf16x8*)(lds + 4096 + (wn * 64 + ni * 16 + cl) * 32 + quad * 8);
#pragma unroll
    for (int mi = 0; mi < 4; mi++)
#pragma unroll
      for (int ni = 0; ni < 4; ni++)
        acc[mi][ni] = __builtin_amdgcn_mfma_f32_16x16x32_bf16(af[mi], bfr[ni], acc[mi][ni], 0, 0, 0);
  }
#pragma unroll
  for (int mi = 0; mi < 4; mi++) {
    int rowb = row0 + wm * 64 + mi * 16 + quad * 4;
#pragma unroll
    for (int r = 0; r < 4; r++) {
      int row = rowb + r;
      if (row >= end) continue;
      long orow = row;
      float scale = 1.f;
      if (doAtomic) { orow = perm[row]; scale = wslot[row] * 2.5f; }
#pragma unroll
      for (int ni = 0; ni < 4; ni++) {
        int col = n0 + wn * 64 + ni * 16 + cl;
        float v = acc[mi][ni][r] * scale;
        if (doAtomic) unsafeAtomicAdd(&Out[orow * HH + col], v);
        else          Out[orow * HH + col] = v;
      }
    }
  }
}

extern "C" void kernel_launch(void* const* d_in, const int* in_sizes, int n_in,
                              void* d_out, int out_size, void* d_ws, size_t ws_size,
                              hipStream_t stream)
{
  const float* x   = (const float*)d_in[0];
  const float* gw  = (const float*)d_in[1];
  const float* eb  = (const float*)d_in[2];
  const float* w1  = (const float*)d_in[3];
  const float* w2  = (const float*)d_in[4];
  const float* sgu = (const float*)d_in[5];
  const float* sd  = (const float*)d_in[6];
  float* out = (float*)d_out;
  char* ws = (char*)d_ws;
  size_t off = 0;
  auto alloc = [&](size_t b) { void* p = ws + off; off += (b + 255) & ~(size_t)255; return p; };
  unsigned short* w1t  = (unsigned short*)alloc((size_t)EE * 2 * II * HH * 2);  // [E][2I][H] bf16
  unsigned short* w2t  = (unsigned short*)alloc((size_t)EE * HH * II * 2);      // [E][H][I]
  unsigned short* sgut = (unsigned short*)alloc((size_t)2 * ISZ * HH * 2);      // [2IS][H]
  unsigned short* sdt  = (unsigned short*)alloc((size_t)HH * ISZ * 2);          // [H][IS]
  unsigned short* xb   = (unsigned short*)alloc((size_t)TT * HH * 2);           // x bf16
  unsigned short* hsb  = (unsigned short*)alloc((size_t)TT * ISZ * 2);          // shared h
  unsigned short* hb   = (unsigned short*)alloc((size_t)TKA * II * 2);          // routed h
  int*   tids   = (int*)alloc((size_t)TKA * 4);
  float* tw     = (float*)alloc((size_t)TKA * 4);
  int*   counts = (int*)alloc(256);
  int*   offs   = (int*)alloc(512);
  int*   cursor = (int*)alloc(256);
  int*   tile_e = (int*)alloc(MAXT * 4);
  int*   tile_r = (int*)alloc(MAXT * 4);
  int*   perm   = (int*)alloc((size_t)TKA * 4);
  float* wslot  = (float*)alloc((size_t)TKA * 4);

  hipMemsetAsync(counts, 0, 256, stream);
  dim3 b256(256);
  // weight transpose+convert (bf16 [N][K] so MFMA frag reads are K-contiguous)
  k_transpose<<<dim3(HH / 64, (2 * II) / 64, EE), b256, 0, stream>>>(w1, w1t, HH, 2 * II);
  k_transpose<<<dim3(II / 64, HH / 64, EE), b256, 0, stream>>>(w2, w2t, II, HH);
  k_transpose<<<dim3(HH / 64, (2 * ISZ) / 64, 1), b256, 0, stream>>>(sgu, sgut, HH, 2 * ISZ);
  k_transpose<<<dim3(ISZ / 64, HH / 64, 1), b256, 0, stream>>>(sd, sdt, ISZ, HH);
  k_cvt<<<dim3((TT * HH) / 1024), b256, 0, stream>>>(x, xb);
  // routing
  k_router<<<dim3(TT), b256, 0, stream>>>(x, gw, eb, tids, tw, counts);
  k_offsets<<<dim3(1), dim3(64), 0, stream>>>(counts, offs, cursor, tile_e, tile_r);
  k_scatter<<<dim3(TKA / 256), b256, 0, stream>>>(tids, tw, cursor, perm, wslot);
  // routed GEMM1 (gathered A via perm) and shared GEMM1
  k_gemm_gu<<<dim3(MAXT, II / 64), b256, 0, stream>>>(xb, perm, w1t, (long)2 * II * HH, HH, II,
                                                      hb, tile_e, tile_r, offs, TKA);
  k_gemm_gu<<<dim3(TT / 128, ISZ / 64), b256, 0, stream>>>(xb, nullptr, sgut, 0, HH, ISZ,
                                                           hsb, nullptr, nullptr, nullptr, TT);
  // shared GEMM2 writes out; routed GEMM2 atomically adds scaled contributions
  k_gemm_down<<<dim3(TT / 128, HH / 128), b256, 0, stream>>>(hsb, sdt, 0, ISZ, out,
                                                             nullptr, nullptr, nullptr, nullptr,
                                                             nullptr, TT, 0);
  k_gemm_down<<<dim3(MAXT, HH / 128), b256, 0, stream>>>(hb, w2t, (long)HH * II, II, out,
                                                         perm, wslot, tile_e, tile_r, offs, TKA, 1);
}

// Round 3
// 969.565 us; speedup vs baseline: 1.2853x; 1.0347x over previous
//
#include <hip/hip_runtime.h>
#include <cstdint>
#include <cstddef>

// Problem constants (match reference config)
#define TT   4096     // tokens
#define HH   1024     // hidden
#define II   512      // moe intermediate
#define EE   64       // experts
#define KT   8        // top-k
#define ISZ  1024     // shared intermediate (I*NSH)
#define TKA  32768    // T*K assignments
#define MAXT 320      // max M-tiles: sum ceil(n_e/128) <= 256+64

typedef __bf16 bf16x8 __attribute__((ext_vector_type(8)));
typedef float  f32x4  __attribute__((ext_vector_type(4)));
typedef unsigned short us8v __attribute__((ext_vector_type(8)));

__device__ __forceinline__ unsigned short f2bf(float f) {
  unsigned u = __float_as_uint(f);
  u += 0x7fffu + ((u >> 16) & 1u);   // RNE (finite inputs only)
  return (unsigned short)(u >> 16);
}

// async global->LDS, 16B/lane; LDS dest is wave-uniform base + lane*16
#define GLDS(gp, lp) __builtin_amdgcn_global_load_lds( \
    (const __attribute__((address_space(1))) void*)(gp), \
    (__attribute__((address_space(3))) void*)(lp), 16, 0, 0)

// LDS bank swizzle: physical 16B slot s at tile-row r holds logical k-chunk
// q = (s - (r>>1)) & 3. Staging lane l (r=l>>2, s=l&3) therefore loads global
// chunk ((l&3)-((l>>3)&3))&3; fragment read of chunk `quad` at row 16a+cl uses
// slot (quad+(cl>>1))&3. Spreads wave64 b128 reads over all 8 bank groups.

// ---------------- transpose + fp32->bf16 convert: in[b][R][C] -> out[b][C][R]
__global__ __launch_bounds__(256) void k_transpose(const float* __restrict__ in,
                                                   unsigned short* __restrict__ out,
                                                   int R, int C) {
  __shared__ float tile[64][65];
  long b = blockIdx.z;
  int r0 = blockIdx.x * 64, c0 = blockIdx.y * 64;
  const float* ip = in + b * (long)R * C;
  unsigned short* op = out + b * (long)R * C;
  int tc = threadIdx.x & 63, tr = threadIdx.x >> 6;
#pragma unroll
  for (int rr = 0; rr < 64; rr += 4)
    tile[tr + rr][tc] = ip[(long)(r0 + tr + rr) * C + (c0 + tc)];
  __syncthreads();
#pragma unroll
  for (int rr = 0; rr < 64; rr += 4)
    op[(long)(c0 + tr + rr) * R + (r0 + tc)] = f2bf(tile[tc][tr + rr]);
}

// ---------------- fp32 -> bf16 elementwise (x)
__global__ __launch_bounds__(256) void k_cvt(const float* __restrict__ in,
                                             unsigned short* __restrict__ out) {
  int i = blockIdx.x * 256 + threadIdx.x;
  float4 v = ((const float4*)in)[i];
  ushort4 o;
  o.x = f2bf(v.x); o.y = f2bf(v.y); o.z = f2bf(v.z); o.w = f2bf(v.w);
  ((ushort4*)out)[i] = o;
}

// ---------------- router: fp64-accurate logits -> sigmoid -> wave-parallel
// grouped top-k (lane = expert, all state in registers, shuffles only).
__global__ __launch_bounds__(256) void k_router(const float* __restrict__ x,
    const float* __restrict__ gw, const float* __restrict__ eb,
    int* __restrict__ topk_ids, float* __restrict__ topk_w, int* __restrict__ counts)
{
  __shared__ float xrow[HH];
  __shared__ float sc[EE];
  int t = blockIdx.x;
  int tid = threadIdx.x;
  for (int i = tid; i < HH; i += 256) xrow[i] = x[(long)t * HH + i];
  __syncthreads();
  int e = tid >> 2, q = tid & 3;          // 4 threads per expert
  const float* w = gw + (long)e * HH;
  double acc = 0.0, acc2 = 0.0;           // 2 chains to halve dep latency
  for (int i = q * 8; i < HH; i += 32) {
    float4 wa = *(const float4*)(w + i);
    float4 wb = *(const float4*)(w + i + 4);
    acc  += (double)wa.x * (double)xrow[i]
          + (double)wa.y * (double)xrow[i + 1]
          + (double)wa.z * (double)xrow[i + 2]
          + (double)wa.w * (double)xrow[i + 3];
    acc2 += (double)wb.x * (double)xrow[i + 4]
          + (double)wb.y * (double)xrow[i + 5]
          + (double)wb.z * (double)xrow[i + 6]
          + (double)wb.w * (double)xrow[i + 7];
  }
  acc += acc2;
  acc += __shfl_down(acc, 2);
  acc += __shfl_down(acc, 1);
  if (q == 0) sc[e] = (float)(1.0 / (1.0 + exp(-acc)));
  __syncthreads();
  if (tid < 64) {                          // wave 0, lane = expert
    int lane = tid;
    float s = sc[lane];
    float sfc = s + eb[lane];
    // --- top-2 within each group of 8 lanes (butterfly top-2 merge)
    float m1 = sfc, m2 = -1e30f;
#pragma unroll
    for (int d = 1; d < 8; d <<= 1) {
      float o1 = __shfl_xor(m1, d);
      float o2 = __shfl_xor(m2, d);
      float hi = fmaxf(m1, o1);
      float lo = fminf(m1, o1);
      m2 = fmaxf(lo, fmaxf(m2, o2));
      m1 = hi;
    }
    float gs = m1 + m2;                    // group score (uniform within group)
    int g = lane >> 3;
    // --- rank my group among 8 (ties -> lowest group idx), select top-4
    int grank = 0;
#pragma unroll
    for (int j = 0; j < 8; j++) {
      float gj = __shfl(gs, j * 8);
      if (gj > gs || (gj == gs && j < g)) grank++;
    }
    bool gsel = grank < 4;
    float mv = gsel ? sfc : 0.0f;          // masked_fill(~mask, 0.0) as in ref
    // --- rank among all 64 (ties -> lowest lane), select top-8
    int rank = 0;
    for (int j = 0; j < 64; j++) {
      float vj = __shfl(mv, j);
      if (vj > mv || (vj == mv && j < lane)) rank++;
    }
    bool sel = rank < KT;
    float ssum = sel ? s : 0.0f;           // renorm sum of RAW scores
#pragma unroll
    for (int d = 1; d < 64; d <<= 1) ssum += __shfl_xor(ssum, d);
    unsigned long long bal = __ballot(sel);
    if (sel) {
      int pos = __popcll(bal & ((1ull << lane) - 1ull));
      topk_ids[(long)t * KT + pos] = lane;
      topk_w[(long)t * KT + pos] = s / ssum;
      atomicAdd(&counts[lane], 1);
    }
  }
}

// ---------------- offsets + static tile table (one wave, shuffle prefix sums)
__global__ void k_offsets(const int* __restrict__ counts, int* __restrict__ offsets,
                          int* __restrict__ cursor, int* __restrict__ tile_e,
                          int* __restrict__ tile_r0)
{
  int lane = threadIdx.x;                  // 64 threads = 1 wave
  int c = counts[lane];
  int xs = c;                              // inclusive prefix sum of counts
#pragma unroll
  for (int d = 1; d < 64; d <<= 1) { int y = __shfl_up(xs, d); if (lane >= d) xs += y; }
  int off = xs - c;                        // exclusive
  offsets[lane] = off;
  cursor[lane] = off;
  if (lane == 63) offsets[EE] = xs;
  int nt = (c + 127) >> 7;                 // M-tiles for this expert
  int tp = nt;                             // inclusive prefix sum of tiles
#pragma unroll
  for (int d = 1; d < 64; d <<= 1) { int y = __shfl_up(tp, d); if (lane >= d) tp += y; }
  int tbase = tp - nt;
  for (int i = 0; i < nt; i++) { tile_e[tbase + i] = lane; tile_r0[tbase + i] = off + i * 128; }
  int total = __shfl(tp, 63);
  for (int i = total + lane; i < MAXT; i += 64) tile_e[i] = -1;
}

// ---------------- scatter assignments into expert-sorted slot order
__global__ __launch_bounds__(256) void k_scatter(const int* __restrict__ ids,
    const float* __restrict__ tw, int* __restrict__ cursor,
    int* __restrict__ perm, float* __restrict__ wslot, int* __restrict__ inv)
{
  int a = blockIdx.x * 256 + threadIdx.x;
  int e = ids[a];
  int pos = atomicAdd(&cursor[e], 1);
  perm[pos] = a >> 3;     // token index
  wslot[pos] = tw[a];
  inv[a] = pos;           // token t, k-th pick -> slot
}

// ---------------- GEMM1 (gate_up) + fused silu*mul. Twin accumulators:
// block: 128 rows x 64 gate cols + 64 up cols. 4 waves (2x2), 16x16x32 bf16 MFMA.
__global__ __launch_bounds__(256) void k_gemm_gu(
    const unsigned short* __restrict__ Abase, const int* __restrict__ perm,
    const unsigned short* __restrict__ Bbase, long eStride, int Kd, int upOff,
    unsigned short* __restrict__ Hout,
    const int* __restrict__ tile_e, const int* __restrict__ tile_r0,
    const int* __restrict__ eoff, int rowsTotal)
{
  __shared__ __align__(16) unsigned short lds[8192];  // A 4096 | Bg 2048 | Bu 2048
  int e = 0, row0, end;
  if (tile_e) {
    e = tile_e[blockIdx.x];
    if (e < 0) return;
    row0 = tile_r0[blockIdx.x];
    end = eoff[e + 1];
  } else { row0 = blockIdx.x * 128; end = rowsTotal; }
  const unsigned short* B = Bbase + (long)e * eStride;
  int n0 = blockIdx.y * 64;
  int tid = threadIdx.x, lane = tid & 63, wave = tid >> 6;
  int wm = wave >> 1, wn = wave & 1;
  int lr = lane >> 2;
  int lkq = ((((lane & 3) - ((lane >> 3) & 3)) & 3)) * 8;  // swizzled k-chunk
  int r0a = row0 + wave * 32 + lr;
  int r1a = r0a + 16;
  int t0 = r0a < rowsTotal ? r0a : rowsTotal - 1;
  int t1 = r1a < rowsTotal ? r1a : rowsTotal - 1;
  if (perm) { t0 = perm[t0]; t1 = perm[t1]; }
  const unsigned short* ap0 = Abase + (long)t0 * Kd + lkq;
  const unsigned short* ap1 = Abase + (long)t1 * Kd + lkq;
  const unsigned short* bg = B + (long)(n0 + wave * 16 + lr) * Kd + lkq;
  const unsigned short* bu = B + (long)(upOff + n0 + wave * 16 + lr) * Kd + lkq;
  unsigned short* lA0 = lds + wave * 1024 + lane * 8;          // rows wave*32..  (+512 = +16 rows)
  unsigned short* lBg = lds + 4096 + wave * 512 + lane * 8;    // rows wave*16..
  unsigned short* lBu = lds + 6144 + wave * 512 + lane * 8;
  f32x4 acc[4][4];
  f32x4 z = {0.f, 0.f, 0.f, 0.f};
  for (int i = 0; i < 4; i++) for (int j = 0; j < 4; j++) acc[i][j] = z;
  int quad = lane >> 4, cl = lane & 15;
  int sw8 = ((quad + ((cl >> 1) & 3)) & 3) * 8;   // swizzled read slot
  for (int k0 = 0; k0 < Kd; k0 += 32) {
    __syncthreads();
    GLDS(ap0 + k0, lA0);
    GLDS(ap1 + k0, lA0 + 512);
    GLDS(bg + k0, lBg);
    GLDS(bu + k0, lBu);
    __syncthreads();
    bf16x8 af[4], bgf[2], buf2[2];
#pragma unroll
    for (int mi = 0; mi < 4; mi++)
      af[mi] = *(const bf16x8*)(lds + (wm * 64 + mi * 16 + cl) * 32 + sw8);
#pragma unroll
    for (int ni = 0; ni < 2; ni++) {
      bgf[ni]  = *(const bf16x8*)(lds + 4096 + (wn * 32 + ni * 16 + cl) * 32 + sw8);
      buf2[ni] = *(const bf16x8*)(lds + 6144 + (wn * 32 + ni * 16 + cl) * 32 + sw8);
    }
#pragma unroll
    for (int mi = 0; mi < 4; mi++) {
#pragma unroll
      for (int ni = 0; ni < 2; ni++) {
        acc[mi][ni]     = __builtin_amdgcn_mfma_f32_16x16x32_bf16(af[mi], bgf[ni],  acc[mi][ni],     0, 0, 0);
        acc[mi][ni + 2] = __builtin_amdgcn_mfma_f32_16x16x32_bf16(af[mi], buf2[ni], acc[mi][ni + 2], 0, 0, 0);
      }
    }
  }
#pragma unroll
  for (int mi = 0; mi < 4; mi++) {
#pragma unroll
    for (int j = 0; j < 2; j++) {
#pragma unroll
      for (int r = 0; r < 4; r++) {
        int row = row0 + wm * 64 + mi * 16 + quad * 4 + r;
        if (row < end) {
          float g = acc[mi][j][r], u = acc[mi][j + 2][r];
          float hv = g * (1.f / (1.f + __expf(-g))) * u;   // silu(g)*u
          Hout[(long)row * upOff + (n0 + wn * 32 + j * 16 + cl)] = f2bf(hv);
        }
      }
    }
  }
}

// ---------------- GEMM2 (down). 128x128 tile.
// mode 0: plain fp32 store to Out (shared path)
// mode 1: scaled bf16 store to Out (routed ys; scale = wslot*2.5)
__global__ __launch_bounds__(256) void k_gemm_down(
    const unsigned short* __restrict__ Abase,
    const unsigned short* __restrict__ Bbase, long eStride, int Kd,
    void* __restrict__ Outv, const float* __restrict__ wslot,
    const int* __restrict__ tile_e, const int* __restrict__ tile_r0,
    const int* __restrict__ eoff, int rowsTotal, int mode)
{
  __shared__ __align__(16) unsigned short lds[8192];  // A 4096 | B 4096
  int e = 0, row0, end;
  if (tile_e) {
    e = tile_e[blockIdx.x];
    if (e < 0) return;
    row0 = tile_r0[blockIdx.x];
    end = eoff[e + 1];
  } else { row0 = blockIdx.x * 128; end = rowsTotal; }
  const unsigned short* B = Bbase + (long)e * eStride;
  int n0 = blockIdx.y * 128;
  int tid = threadIdx.x, lane = tid & 63, wave = tid >> 6;
  int wm = wave >> 1, wn = wave & 1;
  int lr = lane >> 2;
  int lkq = ((((lane & 3) - ((lane >> 3) & 3)) & 3)) * 8;  // swizzled k-chunk
  int r0a = row0 + wave * 32 + lr;
  int r1a = r0a + 16;
  int t0 = r0a < rowsTotal ? r0a : rowsTotal - 1;
  int t1 = r1a < rowsTotal ? r1a : rowsTotal - 1;
  const unsigned short* ap0 = Abase + (long)t0 * Kd + lkq;
  const unsigned short* ap1 = Abase + (long)t1 * Kd + lkq;
  const unsigned short* bp0 = B + (long)(n0 + wave * 32 + lr) * Kd + lkq;
  const unsigned short* bp1 = bp0 + (long)16 * Kd;
  unsigned short* lA0 = lds + wave * 1024 + lane * 8;
  unsigned short* lB0 = lds + 4096 + wave * 1024 + lane * 8;
  f32x4 acc[4][4];
  f32x4 z = {0.f, 0.f, 0.f, 0.f};
  for (int i = 0; i < 4; i++) for (int j = 0; j < 4; j++) acc[i][j] = z;
  int quad = lane >> 4, cl = lane & 15;
  int sw8 = ((quad + ((cl >> 1) & 3)) & 3) * 8;   // swizzled read slot
  for (int k0 = 0; k0 < Kd; k0 += 32) {
    __syncthreads();
    GLDS(ap0 + k0, lA0);
    GLDS(ap1 + k0, lA0 + 512);
    GLDS(bp0 + k0, lB0);
    GLDS(bp1 + k0, lB0 + 512);
    __syncthreads();
    bf16x8 af[4], bfr[4];
#pragma unroll
    for (int mi = 0; mi < 4; mi++)
      af[mi] = *(const bf16x8*)(lds + (wm * 64 + mi * 16 + cl) * 32 + sw8);
#pragma unroll
    for (int ni = 0; ni < 4; ni++)
      bfr[ni] = *(const bf16x8*)(lds + 4096 + (wn * 64 + ni * 16 + cl) * 32 + sw8);
#pragma unroll
    for (int mi = 0; mi < 4; mi++)
#pragma unroll
      for (int ni = 0; ni < 4; ni++)
        acc[mi][ni] = __builtin_amdgcn_mfma_f32_16x16x32_bf16(af[mi], bfr[ni], acc[mi][ni], 0, 0, 0);
  }
#pragma unroll
  for (int mi = 0; mi < 4; mi++) {
    int rowb = row0 + wm * 64 + mi * 16 + quad * 4;
#pragma unroll
    for (int r = 0; r < 4; r++) {
      int row = rowb + r;
      if (row >= end) continue;
      if (mode) {
        unsigned short* Y = (unsigned short*)Outv;
        float scale = wslot[row] * 2.5f;
#pragma unroll
        for (int ni = 0; ni < 4; ni++) {
          int col = n0 + wn * 64 + ni * 16 + cl;
          Y[(long)row * HH + col] = f2bf(acc[mi][ni][r] * scale);
        }
      } else {
        float* O = (float*)Outv;
#pragma unroll
        for (int ni = 0; ni < 4; ni++) {
          int col = n0 + wn * 64 + ni * 16 + cl;
          O[(long)row * HH + col] = acc[mi][ni][r];
        }
      }
    }
  }
}

// ---------------- combine: out[t] += sum_k ys[inv[t][k]]  (ys pre-scaled)
__global__ __launch_bounds__(256) void k_combine(const unsigned short* __restrict__ ys,
    const int* __restrict__ inv, float* __restrict__ out)
{
  int idx = blockIdx.x * 256 + threadIdx.x;   // T * 128 threads
  int t = idx >> 7, c0 = (idx & 127) << 3;
  const int* ip = inv + (long)t * KT;
  float* op = out + (long)t * HH + c0;
  float4 o0 = *(float4*)op;
  float4 o1 = *(float4*)(op + 4);
  float a[8] = {o0.x, o0.y, o0.z, o0.w, o1.x, o1.y, o1.z, o1.w};
#pragma unroll
  for (int k = 0; k < KT; k++) {
    us8v v = *(const us8v*)(ys + (long)ip[k] * HH + c0);
#pragma unroll
    for (int j = 0; j < 8; j++) a[j] += __uint_as_float((unsigned)v[j] << 16);
  }
  *(float4*)op = make_float4(a[0], a[1], a[2], a[3]);
  *(float4*)(op + 4) = make_float4(a[4], a[5], a[6], a[7]);
}

extern "C" void kernel_launch(void* const* d_in, const int* in_sizes, int n_in,
                              void* d_out, int out_size, void* d_ws, size_t ws_size,
                              hipStream_t stream)
{
  const float* x   = (const float*)d_in[0];
  const float* gw  = (const float*)d_in[1];
  const float* eb  = (const float*)d_in[2];
  const float* w1  = (const float*)d_in[3];
  const float* w2  = (const float*)d_in[4];
  const float* sgu = (const float*)d_in[5];
  const float* sd  = (const float*)d_in[6];
  float* out = (float*)d_out;
  char* ws = (char*)d_ws;
  size_t off = 0;
  auto alloc = [&](size_t b) { void* p = ws + off; off += (b + 255) & ~(size_t)255; return p; };
  unsigned short* w1t  = (unsigned short*)alloc((size_t)EE * 2 * II * HH * 2);  // [E][2I][H] bf16
  unsigned short* w2t  = (unsigned short*)alloc((size_t)EE * HH * II * 2);      // [E][H][I]
  unsigned short* sgut = (unsigned short*)alloc((size_t)2 * ISZ * HH * 2);      // [2IS][H]
  unsigned short* sdt  = (unsigned short*)alloc((size_t)HH * ISZ * 2);          // [H][IS]
  unsigned short* xb   = (unsigned short*)alloc((size_t)TT * HH * 2);           // x bf16
  unsigned short* hsb  = (unsigned short*)alloc((size_t)TT * ISZ * 2);          // shared h
  unsigned short* hb   = (unsigned short*)alloc((size_t)TKA * II * 2);          // routed h
  unsigned short* ys   = (unsigned short*)alloc((size_t)TKA * HH * 2);          // routed down out (scaled bf16)
  int*   tids   = (int*)alloc((size_t)TKA * 4);
  float* tw     = (float*)alloc((size_t)TKA * 4);
  int*   counts = (int*)alloc(256);
  int*   offs   = (int*)alloc(512);
  int*   cursor = (int*)alloc(256);
  int*   tile_e = (int*)alloc(MAXT * 4);
  int*   tile_r = (int*)alloc(MAXT * 4);
  int*   perm   = (int*)alloc((size_t)TKA * 4);
  float* wslot  = (float*)alloc((size_t)TKA * 4);
  int*   inv    = (int*)alloc((size_t)TKA * 4);

  hipMemsetAsync(counts, 0, 256, stream);
  dim3 b256(256);
  // weight transpose+convert (bf16 [N][K] so MFMA frag reads are K-contiguous)
  k_transpose<<<dim3(HH / 64, (2 * II) / 64, EE), b256, 0, stream>>>(w1, w1t, HH, 2 * II);
  k_transpose<<<dim3(II / 64, HH / 64, EE), b256, 0, stream>>>(w2, w2t, II, HH);
  k_transpose<<<dim3(HH / 64, (2 * ISZ) / 64, 1), b256, 0, stream>>>(sgu, sgut, HH, 2 * ISZ);
  k_transpose<<<dim3(ISZ / 64, HH / 64, 1), b256, 0, stream>>>(sd, sdt, ISZ, HH);
  k_cvt<<<dim3((TT * HH) / 1024), b256, 0, stream>>>(x, xb);
  // routing
  k_router<<<dim3(TT), b256, 0, stream>>>(x, gw, eb, tids, tw, counts);
  k_offsets<<<dim3(1), dim3(64), 0, stream>>>(counts, offs, cursor, tile_e, tile_r);
  k_scatter<<<dim3(TKA / 256), b256, 0, stream>>>(tids, tw, cursor, perm, wslot, inv);
  // routed path: GEMM1 (gathered A via perm) -> ys (scaled bf16)
  k_gemm_gu<<<dim3(MAXT, II / 64), b256, 0, stream>>>(xb, perm, w1t, (long)2 * II * HH, HH, II,
                                                      hb, tile_e, tile_r, offs, TKA);
  k_gemm_down<<<dim3(MAXT, HH / 128), b256, 0, stream>>>(hb, w2t, (long)HH * II, II, (void*)ys,
                                                         wslot, tile_e, tile_r, offs, TKA, 1);
  // shared path -> out (fp32)
  k_gemm_gu<<<dim3(TT / 128, ISZ / 64), b256, 0, stream>>>(xb, nullptr, sgut, 0, HH, ISZ,
                                                           hsb, nullptr, nullptr, nullptr, TT);
  k_gemm_down<<<dim3(TT / 128, HH / 128), b256, 0, stream>>>(hsb, sdt, 0, ISZ, (void*)out,
                                                             nullptr, nullptr, nullptr, nullptr, TT, 0);
  // combine: out += gathered ys
  k_combine<<<dim3(TT * 128 / 256), b256, 0, stream>>>(ys, inv, out);
}